// Round 6
// baseline (542.282 us; speedup 1.0000x reference)
//
#include <hip/hip_runtime.h>
#include <cstdint>
#include <cstddef>

// GTM forward: out[0] = -ll, out[1..] = R^T [N=131072][K=360]
//   E'_k(n) = b*(Y_k . t_n - 0.5*||Y_k||^2)   (||t||^2 shift cancels in softmax AND in log s)
//   R[:,n] = softmax_k(E'), ll_n = 256*log(b/2pi) + log(sum exp(E'-max)) - log 360
// GEMM via bf16 hi/lo split (3 MFMA passes) for fp32-grade accuracy on E.
//
// R4 -> R5: R4's dbuf was neutral (234 us, MfmaUtil 28%) — the syncthreads
// vmcnt(0) drain of the A global_load_lds is the structural ceiling (catalog
// m131-m141). Fix: A (768 KB, read by all blocks -> L2-resident) is no longer
// LDS-staged at all; fragments load straight from global as coalesced 1KB/wave
// dwordx4 with compiler-counted vmcnt — never behind a barrier. Only the B
// (t) tile stays in LDS, synced with raw s_barrier + explicit lgkmcnt(0):
// NO vmcnt drain anywhere in the K-loop. k_prep: 4 parallel FMA chains
// (was a serial latency-bound 145-load chain), no atomics, k_init folded in.
// (R5 bench was an infra timeout; resubmitted unchanged after desk audit.)

#define KNODES 360
#define MRBF   145
#define DD     512
#define NTOT   131072
#define BN     128
#define NBLK   (NTOT / BN)     // 1024
#define NKS    16              // K-steps of 32
#define ACHUNK 24576           // bytes per A K-chunk: 384 rows * 32 k * 2 B

// LDS: B dbuf 2x16384 @0 | (epilogue: Rt 2x27648 overlays B) | red @57344
#define LDS_RED 57344
#define LDS_TOT 61440

typedef float  f32x4  __attribute__((ext_vector_type(4)));
typedef short  s16x8  __attribute__((ext_vector_type(8)));
typedef __bf16 bf16x8 __attribute__((ext_vector_type(8)));

static __device__ __forceinline__ bf16x8 as_bf(s16x8 v) { return __builtin_bit_cast(bf16x8, v); }

// round-to-nearest-even fp32 -> bf16 (data has no NaN/Inf)
static __device__ __forceinline__ unsigned short f2bf(float x) {
  unsigned u = __float_as_uint(x);
  u += 0x7FFFu + ((u >> 16) & 1u);
  return (unsigned short)(u >> 16);
}
static __device__ __forceinline__ float bf2f(unsigned short h) {
  return __uint_as_float(((unsigned)h) << 16);
}

// ---------------------------------------------------------------------------
// prep: Y = phi@W, one element per thread (360 blocks x 512 threads).
// Stores Y hi/lo bf16 in LINEAR chunked layout: chunk (d>>5) | row k | (d&31).
// Rows 360..383 of A are never written: k_main reads ws poison there (finite
// small values) and the epilogue forces E=-1e30 for those rows.
// ---------------------------------------------------------------------------
__global__ __launch_bounds__(512) void k_prep(const float* __restrict__ W,
                                              unsigned short* __restrict__ ahi,
                                              unsigned short* __restrict__ alo,
                                              float* __restrict__ cbuf,
                                              float* __restrict__ llbuf) {
  const int k   = blockIdx.x;    // latent row 0..359
  const int tid = threadIdx.x;   // = d, 0..511

  __shared__ float phi[MRBF];
  __shared__ float rw[8];

  if (tid < MRBF) {
    float p = 1.0f;                              // bias column (m == 144)
    if (tid < MRBF - 1) {
      const float ca = -11.0f / 12.0f + (1.0f / 6.0f) * (float)(tid / 12);
      const float cb = -11.0f / 12.0f + (1.0f / 6.0f) * (float)(tid % 12);
      const float xa = -1.0f + (2.0f / 19.0f) * (float)(k / 18);
      const float xb = -1.0f + (2.0f / 17.0f) * (float)(k % 18);
      const float dx = xa - ca, dy = xb - cb;
      p = expf(-3.0f * (dx * dx + dy * dy));     // exp(-d2/(2*sigma)), sigma=1/6
    }
    phi[tid] = p;
  }
  __syncthreads();

  // 4 independent FMA chains so the 145 W loads pipeline (was latency-serial)
  float y0 = 0.0f, y1 = 0.0f, y2 = 0.0f, y3 = 0.0f;
  #pragma unroll 4
  for (int m = 0; m < 144; m += 4) {
    y0 = fmaf(phi[m],     W[(m)     * DD + tid], y0);
    y1 = fmaf(phi[m + 1], W[(m + 1) * DD + tid], y1);
    y2 = fmaf(phi[m + 2], W[(m + 2) * DD + tid], y2);
    y3 = fmaf(phi[m + 3], W[(m + 3) * DD + tid], y3);
  }
  const float y = ((y0 + y1) + (y2 + y3)) + W[144 * DD + tid];  // phi[144]=1

  const unsigned short h = f2bf(y);
  const unsigned short l = f2bf(y - bf2f(h));
  const int idx = (tid >> 5) * (ACHUNK / 2) + k * 32 + (tid & 31);
  ahi[idx] = h;
  alo[idx] = l;

  float q = y * y;
  #pragma unroll
  for (int mk = 1; mk < 64; mk <<= 1) q += __shfl_xor(q, mk);
  if ((tid & 63) == 0) rw[tid >> 6] = q;
  __syncthreads();
  if (tid == 0) {
    float s = 0.0f;
    #pragma unroll
    for (int i = 0; i < 8; ++i) s += rw[i];
    cbuf[k] = 0.5f * s;
    if (k == 0) llbuf[0] = 0.0f;   // runs before k_main (stream-ordered)
  }
}

// ---------------------------------------------------------------------------
// main: 8 waves (4 m-quarters x 2 n-halves), 384 rows x 128 cols per block.
// A fragments direct-from-global (L2-resident), B (t) via dbuf LDS with raw
// s_barrier + lgkmcnt(0) only. bf16x3 MFMA + fused softmax + transposed store.
// ---------------------------------------------------------------------------
__global__ __launch_bounds__(512, 2) void k_main(const float* __restrict__ t,
                                                 const float* __restrict__ beta,
                                                 const unsigned short* __restrict__ ahi,
                                                 const unsigned short* __restrict__ alo,
                                                 const float* __restrict__ cbuf,
                                                 float* __restrict__ out,
                                                 float* __restrict__ llbuf) {
  __shared__ __align__(16) char smem[LDS_TOT];
  const int tid  = threadIdx.x;
  const int lane = tid & 63;
  const int wv   = tid >> 6;     // 0..7
  const int wm   = wv & 3;       // m-quarter: rows [wm*96, wm*96+96)
  const int g    = wv >> 2;      // n-half:   cols [g*64, g*64+64)
  const int col  = lane & 15;
  const int kg   = lane >> 4;
  const int n0   = blockIdx.x * BN;
  const float b  = beta[0];

  f32x4 acc[6][4] = {};          // rows = wm*96+i*16+kg*4+r, col = g*64+j*16+col

  const float* tsrc = t + (size_t)(n0 + (tid >> 2)) * DD + (tid & 3) * 8;
  const int brow  = tid >> 2;    // B tile row = n index 0..127
  const int bbyte = ((brow * 64 + (tid & 3) * 16) ^ ((brow & 7) << 4));

  // A fragment base (linear layout): row m = wm*96 + i*16 + col, k-off kg*16 B
  const char* aposH = (const char*)ahi + (wm * 96 + col) * 64 + kg * 16;
  const char* aposL = (const char*)alo + (wm * 96 + col) * 64 + kg * 16;
  // B fragment base inside half-buffer; (nn&7)==(col&7) since j*16 % 8 == 0
  const int bfbase = (((g * 64 + col) * 64 + kg * 16) ^ ((col & 7) << 4));

  // convert 8 t-floats -> bf16 hi/lo and ds_write swizzled into buffer sbuf
  auto bconv = [&](int sbuf, float4 v0, float4 v1) {
    char* db = smem + sbuf * 16384;
    const float f[8] = {v0.x, v0.y, v0.z, v0.w, v1.x, v1.y, v1.z, v1.w};
    s16x8 hv, lv;
    #pragma unroll
    for (int q = 0; q < 8; ++q) {
      const unsigned short h = f2bf(f[q]);
      hv[q] = (short)h;
      lv[q] = (short)f2bf(f[q] - bf2f(h));
    }
    *(s16x8*)(db + bbyte) = hv;
    *(s16x8*)(db + 8192 + bbyte) = lv;
  };

  // One K-step: prefetch t(ks+2) into TP*, consume TU* (t data for ks+1) into
  // buf CUR^1, read B frags from buf CUR, A frags from global, 72 MFMA.
  // Raw barrier: only lgkmcnt(0) before it — A loads never drained.
#define STEP(KS, CUR, TU0, TU1, TP0, TP1)                                      \
  {                                                                            \
    const int ks_ = (KS);                                                      \
    if (ks_ < NKS - 2) {                                                       \
      TP0 = *(const float4*)(tsrc + (ks_ + 2) * 32);                           \
      TP1 = *(const float4*)(tsrc + (ks_ + 2) * 32 + 4);                       \
    }                                                                          \
    s16x8 Ah[6], Al[6];                                                        \
    _Pragma("unroll")                                                          \
    for (int i = 0; i < 6; ++i) {                                              \
      Ah[i] = *(const s16x8*)(aposH + ks_ * ACHUNK + i * 1024);                \
      Al[i] = *(const s16x8*)(aposL + ks_ * ACHUNK + i * 1024);                \
    }                                                                          \
    const char* Bb = smem + (CUR) * 16384;                                     \
    s16x8 Bh[4], Bl[4];                                                        \
    _Pragma("unroll")                                                          \
    for (int j = 0; j < 4; ++j) {                                              \
      Bh[j] = *(const s16x8*)(Bb + bfbase + j * 1024);                         \
      Bl[j] = *(const s16x8*)(Bb + 8192 + bfbase + j * 1024);                  \
    }                                                                          \
    if (ks_ < NKS - 1) bconv((CUR) ^ 1, TU0, TU1);                             \
    __builtin_amdgcn_s_setprio(1);                                             \
    _Pragma("unroll")                                                          \
    for (int i = 0; i < 6; ++i) {                                              \
      _Pragma("unroll")                                                        \
      for (int j = 0; j < 4; ++j) {                                            \
        acc[i][j] = __builtin_amdgcn_mfma_f32_16x16x32_bf16(as_bf(Ah[i]), as_bf(Bh[j]), acc[i][j], 0, 0, 0); \
        acc[i][j] = __builtin_amdgcn_mfma_f32_16x16x32_bf16(as_bf(Ah[i]), as_bf(Bl[j]), acc[i][j], 0, 0, 0); \
        acc[i][j] = __builtin_amdgcn_mfma_f32_16x16x32_bf16(as_bf(Al[i]), as_bf(Bh[j]), acc[i][j], 0, 0, 0); \
      }                                                                        \
    }                                                                          \
    __builtin_amdgcn_s_setprio(0);                                             \
    asm volatile("s_waitcnt lgkmcnt(0)" ::: "memory");                         \
    __builtin_amdgcn_s_barrier();                                              \
    __builtin_amdgcn_sched_barrier(0);                                         \
  }

  // prologue: B chunk 0 straight into buf0; preload t chunk 1 into regs
  {
    const float4 v0 = *(const float4*)(tsrc);
    const float4 v1 = *(const float4*)(tsrc + 4);
    bconv(0, v0, v1);
  }
  float4 ta0 = *(const float4*)(tsrc + 32);
  float4 ta1 = *(const float4*)(tsrc + 36);
  float4 tb0 = {}, tb1 = {};
  asm volatile("s_waitcnt lgkmcnt(0)" ::: "memory");
  __builtin_amdgcn_s_barrier();
  __builtin_amdgcn_sched_barrier(0);

  for (int kk = 0; kk < 8; ++kk) {
    STEP(2 * kk,     0, ta0, ta1, tb0, tb1)
    STEP(2 * kk + 1, 1, tb0, tb1, ta0, ta1)
  }
#undef STEP

  // ---- epilogue: E = b*(dot - c); per-group column softmax over 384 rows
  float* red  = (float*)(smem + LDS_RED + g * 2048);  // [4 wm][64 cols]
  float* red2 = red + 256;

  float carr[6][4];
  #pragma unroll
  for (int i = 0; i < 6; ++i) {
    #pragma unroll
    for (int r = 0; r < 4; ++r) {
      const int row = wm * 96 + i * 16 + kg * 4 + r;
      carr[i][r] = (row < KNODES) ? cbuf[row] : 1.0e30f;  // pad rows -> E ~ -1e30
    }
  }

  float colmax[4] = {-3.0e38f, -3.0e38f, -3.0e38f, -3.0e38f};
  #pragma unroll
  for (int i = 0; i < 6; ++i) {
    #pragma unroll
    for (int j = 0; j < 4; ++j) {
      #pragma unroll
      for (int r = 0; r < 4; ++r) {
        acc[i][j][r] = (acc[i][j][r] - carr[i][r]) * b;
        colmax[j] = fmaxf(colmax[j], acc[i][j][r]);
      }
    }
  }
  #pragma unroll
  for (int j = 0; j < 4; ++j) {
    colmax[j] = fmaxf(colmax[j], __shfl_xor(colmax[j], 16));
    colmax[j] = fmaxf(colmax[j], __shfl_xor(colmax[j], 32));
  }
  if (lane < 16) {
    #pragma unroll
    for (int j = 0; j < 4; ++j) red[wm * 64 + j * 16 + lane] = colmax[j];
  }
  __syncthreads();

  float fullmax[4];
  float colsum[4] = {0.0f, 0.0f, 0.0f, 0.0f};
  #pragma unroll
  for (int j = 0; j < 4; ++j) {
    const int cc = j * 16 + col;
    fullmax[j] = fmaxf(fmaxf(red[cc], red[64 + cc]), fmaxf(red[128 + cc], red[192 + cc]));
  }
  #pragma unroll
  for (int i = 0; i < 6; ++i) {
    #pragma unroll
    for (int j = 0; j < 4; ++j) {
      #pragma unroll
      for (int r = 0; r < 4; ++r) {
        const float p = expf(acc[i][j][r] - fullmax[j]);
        acc[i][j][r] = p;
        colsum[j] += p;
      }
    }
  }
  #pragma unroll
  for (int j = 0; j < 4; ++j) {
    colsum[j] += __shfl_xor(colsum[j], 16);
    colsum[j] += __shfl_xor(colsum[j], 32);
  }
  if (lane < 16) {
    #pragma unroll
    for (int j = 0; j < 4; ++j) red2[wm * 64 + j * 16 + lane] = colsum[j];
  }
  __syncthreads();

  float s[4];
  #pragma unroll
  for (int j = 0; j < 4; ++j) {
    const int cc = j * 16 + col;
    s[j] = (red2[cc] + red2[64 + cc]) + (red2[128 + cc] + red2[192 + cc]);
  }

  // log-likelihood partial: per group, wave wm==0, lanes 0..15 cover 64 cols
  float llp = 0.0f;
  if (lane < 16) {
    #pragma unroll
    for (int j = 0; j < 4; ++j) llp += logf(s[j]);
  }
  if (wm == 0) {
    #pragma unroll
    for (int mk = 1; mk < 64; mk <<= 1) llp += __shfl_xor(llp, mk);
    if (lane == 0) atomicAdd(llbuf, llp);
  }

  float inv[4];
  #pragma unroll
  for (int j = 0; j < 4; ++j) inv[j] = 1.0f / s[j];
  #pragma unroll
  for (int i = 0; i < 6; ++i) {
    #pragma unroll
    for (int j = 0; j < 4; ++j) acc[i][j] *= inv[j];
  }

  // ---- transpose via LDS (stride 18) + coalesced column stores.
  // Per-group Rt buffers overlay the (dead) B double-buffer region.
  float* Rt = (float*)(smem + g * 28672);  // [384][18] f32 = 27648 B
  #pragma unroll
  for (int jj = 0; jj < 4; ++jj) {
    __syncthreads();
    #pragma unroll
    for (int i = 0; i < 6; ++i) {
      const int mbase = wm * 96 + i * 16 + kg * 4;
      #pragma unroll
      for (int r = 0; r < 4; ++r) Rt[(mbase + r) * 18 + col] = acc[i][jj][r];
    }
    __syncthreads();
    #pragma unroll
    for (int c2l = 0; c2l < 4; ++c2l) {
      const int cc = wm * 4 + c2l;
      const size_t n = (size_t)(n0 + g * 64 + jj * 16 + cc);
      #pragma unroll
      for (int i2 = 0; i2 < 6; ++i2) {
        const int m = lane + 64 * i2;
        if (m < KNODES) out[1 + n * KNODES + m] = Rt[m * 18 + cc];
      }
    }
  }
}

// ---------------------------------------------------------------------------
__global__ void k_fin(const float* __restrict__ beta, const float* __restrict__ llbuf,
                      float* __restrict__ out) {
  const float b = beta[0];
  // -ll = -(256*log(b/2pi) - log(360) + (1/N)*sum log s)
  out[0] = -(256.0f * logf(b * (1.0f / 6.283185307179586f)) - logf(360.0f)
             + llbuf[0] * (1.0f / 131072.0f));
}

extern "C" void kernel_launch(void* const* d_in, const int* in_sizes, int n_in,
                              void* d_out, int out_size, void* d_ws, size_t ws_size,
                              hipStream_t stream) {
  const float* t    = (const float*)d_in[0];
  const float* W    = (const float*)d_in[1];
  const float* beta = (const float*)d_in[2];
  float* out = (float*)d_out;

  // ws layout: A_hi[393216 B] | A_lo[393216 B] | c[1536 B] | ll[4 B]
  unsigned short* ahi = (unsigned short*)d_ws;
  unsigned short* alo = (unsigned short*)((char*)d_ws + 393216);
  float* cbuf  = (float*)((char*)d_ws + 786432);
  float* llbuf = (float*)((char*)d_ws + 787968);

  hipLaunchKernelGGL(k_prep, dim3(KNODES), dim3(512), 0, stream, W, ahi, alo, cbuf, llbuf);
  hipLaunchKernelGGL(k_main, dim3(NBLK), dim3(512), 0, stream,
                     t, beta, ahi, alo, cbuf, out, llbuf);
  hipLaunchKernelGGL(k_fin, dim3(1), dim3(1), 0, stream, beta, llbuf, out);
}